// Round 2
// baseline (1202.953 us; speedup 1.0000x reference)
//
#include <hip/hip_runtime.h>
#include <cstdint>
#include <cstddef>

// W8A8LinearStatic: out[m][n] = (sum_k round(x[m][k]/s_act) * W[n][k]) * out_scales[n]
// M=8192 (B*S), N=11008, K=4096. fp16 GEMM (exact: |q_x|<2048 integer, |W|<=127).
//
// R4: 256x256 tile, 8 waves (2Mx4N, 128x64 each), 32x32x16_f16 MFMA (11% faster
// pipe than 16x16x32), read-balanced window (16/0/8/0 ds_reads with counted
// lgkmcnt), all next-tile stages front-loaded to ph0 (>=3 phases of latency
// slack), 6 barriers/window, counted vmcnt(2) only at window end.

#define M_DIM 8192
#define N_DIM 11008
#define K_DIM 4096

#define G_TM 32                 // M/256
#define G_TN 43                 // N/256
#define G_NB (G_TM * G_TN)      // 1376 = 8 XCDs * 172
#define NT   (K_DIM / 64)       // 64 K-tiles of BK=64

#define FB_TM 64
#define FB_TN 86
#define FB_NB (FB_TM * FB_TN)
#define FB_GROUP 16

typedef _Float16 half8  __attribute__((ext_vector_type(8)));
typedef float    f32x4  __attribute__((ext_vector_type(4)));
typedef float    f32x16 __attribute__((ext_vector_type(16)));

#define GLOBAL_AS(p) ((const __attribute__((address_space(1))) void*)(p))
#define LDS_AS(p)    ((__attribute__((address_space(3))) void*)(p))

#define MFMA16(a,b,c) __builtin_amdgcn_mfma_f32_16x16x32_f16((a),(b),(c),0,0,0)
#define MFMA32(a,b,c) __builtin_amdgcn_mfma_f32_32x32x16_f16((a),(b),(c),0,0,0)

#define BARRIER() do { asm volatile("" ::: "memory"); \
                       __builtin_amdgcn_s_barrier();  \
                       asm volatile("" ::: "memory"); } while (0)

// ---------------- quantize activations: q = rint(x * (1/s)), store fp16 ----------------
__global__ __launch_bounds__(256) void quant_x_kernel(
    const float* __restrict__ x, const float* __restrict__ act_s,
    _Float16* __restrict__ qx)
{
    const float inv = 1.0f / act_s[0];
    size_t idx = ((size_t)blockIdx.x * 256u + threadIdx.x) * 8u;
    const float4* p = (const float4*)(x + idx);
    float4 v0 = p[0];
    float4 v1 = p[1];
    half8 h;
    h[0] = (_Float16)rintf(v0.x * inv);
    h[1] = (_Float16)rintf(v0.y * inv);
    h[2] = (_Float16)rintf(v0.z * inv);
    h[3] = (_Float16)rintf(v0.w * inv);
    h[4] = (_Float16)rintf(v1.x * inv);
    h[5] = (_Float16)rintf(v1.y * inv);
    h[6] = (_Float16)rintf(v1.z * inv);
    h[7] = (_Float16)rintf(v1.w * inv);
    *(half8*)(qx + idx) = h;
}

// ---------------- convert weights: int32 (int8-valued) -> fp16 ----------------
__global__ __launch_bounds__(256) void quant_w_kernel(
    const int* __restrict__ w, _Float16* __restrict__ qw)
{
    size_t idx = ((size_t)blockIdx.x * 256u + threadIdx.x) * 8u;
    const int4* p = (const int4*)(w + idx);
    int4 v0 = p[0];
    int4 v1 = p[1];
    half8 h;
    h[0] = (_Float16)v0.x;
    h[1] = (_Float16)v0.y;
    h[2] = (_Float16)v0.z;
    h[3] = (_Float16)v0.w;
    h[4] = (_Float16)v1.x;
    h[5] = (_Float16)v1.y;
    h[6] = (_Float16)v1.z;
    h[7] = (_Float16)v1.w;
    *(half8*)(qw + idx) = h;
}

// ---------------- staging: one 128-row half-tile (2 x global_load_lds 16B) ----------
// LDS per buffer: 256 rows x 8 chunks of 16B, linear write; stored slot s of
// row r holds GLOBAL chunk s ^ (r&7) (source pre-swizzle; reads apply the same
// XOR -> involution).  src includes (row0 + tid>>3)*K + ((tid&7)^((tid>>3)&7))*8;
// lds includes buffer base + tid*8.
__device__ __forceinline__ void stage_half(const _Float16* __restrict__ src,
                                           _Float16* lds, int koff, int hrow)
{
    const _Float16* s = src + (size_t)hrow * K_DIM + koff;
    __builtin_amdgcn_global_load_lds(GLOBAL_AS(s),
        LDS_AS(lds + hrow * 64), 16, 0, 0);
    __builtin_amdgcn_global_load_lds(GLOBAL_AS(s + (size_t)64 * K_DIM),
        LDS_AS(lds + hrow * 64 + 4096), 16, 0, 0);
}

// ---------------- one K-tile window = 4 phases, 32x32x16 MFMA ----------------
// Per wave: 4x2 output frags of 32x32 (128x64), 4 K-slices of 16.
// Frag reads: A(fr,ks): row = wm*128 + fr*32 + (l&31), chunk = 2ks+(l>>5);
//             B(fc,ks): row = wn*64  + fc*32 + (l&31), same chunk form.
// Read schedule: ph0: af(fr0,1) 8 + bf0 4 + bf1 4; ph2: af(fr2,3) 8.
// Stage schedule (SM==2): ph0: BH0,BH1,AH1 of t+1 (6 loads -> >=3 phases of
// slack); ph3: AH0 of t+2 into current A buffer (rows 0-127 free after ph2).
// vmcnt(2) at window end keeps only AH0(t+2) in flight.
// SM: 2 steady / 1 (t==NT-2: stage t+1 only, vmcnt(0)) / 0 (t==NT-1: compute).
template<int SM>
__device__ __forceinline__ void gemm_window(
    const _Float16* __restrict__ aSrc, const _Float16* __restrict__ bSrc,
    int koff,
    const _Float16* aT, const _Float16* bT,   // current LDS buffers
    _Float16* aN, _Float16* bN,               // next buffers (+ tid*8)
    _Float16* aC,                             // current A buffer (+ tid*8)
    int aRow, int bRow, const int (&so)[4],
    f32x16 (&acc)[4][2])
{
    half8 af[2][4], bf0[4], bf1[4];

    // ---- phase 0: 16 ds_reads + all 6 next-tile stage issues; quad (fr01, fc0)
#pragma unroll
    for (int fr = 0; fr < 2; ++fr)
#pragma unroll
        for (int ks = 0; ks < 4; ++ks)
            af[fr][ks] = *(const half8*)(aT + aRow + fr * 2048 + so[ks]);
#pragma unroll
    for (int ks = 0; ks < 4; ++ks)
        bf0[ks] = *(const half8*)(bT + bRow + so[ks]);
#pragma unroll
    for (int ks = 0; ks < 4; ++ks)
        bf1[ks] = *(const half8*)(bT + bRow + 2048 + so[ks]);
    if (SM >= 1) {
        stage_half(bSrc, bN, koff + 64, 0);     // (t+1, BH0)
        stage_half(bSrc, bN, koff + 64, 128);   // (t+1, BH1)
        stage_half(aSrc, aN, koff + 64, 128);   // (t+1, AH1)
    }
    asm volatile("s_waitcnt lgkmcnt(8)" ::: "memory");   // af done
    BARRIER();
    asm volatile("s_waitcnt lgkmcnt(4)" ::: "memory");   // bf0 done, bf1 in flight
    __builtin_amdgcn_s_setprio(1);
#pragma unroll
    for (int ks = 0; ks < 4; ++ks) {
        acc[0][0] = MFMA32(af[0][ks], bf0[ks], acc[0][0]);
        acc[1][0] = MFMA32(af[1][ks], bf0[ks], acc[1][0]);
    }
    __builtin_amdgcn_s_setprio(0);
    BARRIER();

    // ---- phase 1: no reads, no waits beyond bf1; quad (fr01, fc1)
    asm volatile("s_waitcnt lgkmcnt(0)" ::: "memory");
    __builtin_amdgcn_s_setprio(1);
#pragma unroll
    for (int ks = 0; ks < 4; ++ks) {
        acc[0][1] = MFMA32(af[0][ks], bf1[ks], acc[0][1]);
        acc[1][1] = MFMA32(af[1][ks], bf1[ks], acc[1][1]);
    }
    __builtin_amdgcn_s_setprio(0);
    BARRIER();

    // ---- phase 2: reload af with fr2,3 (A rows +64..127); quad (fr23, fc1)
#pragma unroll
    for (int fr = 0; fr < 2; ++fr)
#pragma unroll
        for (int ks = 0; ks < 4; ++ks)
            af[fr][ks] = *(const half8*)(aT + aRow + 4096 + fr * 2048 + so[ks]);
    asm volatile("s_waitcnt lgkmcnt(4)" ::: "memory");
    BARRIER();
    asm volatile("s_waitcnt lgkmcnt(0)" ::: "memory");
    __builtin_amdgcn_s_setprio(1);
#pragma unroll
    for (int ks = 0; ks < 4; ++ks) {
        acc[2][1] = MFMA32(af[0][ks], bf1[ks], acc[2][1]);
        acc[3][1] = MFMA32(af[1][ks], bf1[ks], acc[3][1]);
    }
    __builtin_amdgcn_s_setprio(0);
    BARRIER();   // all waves' A reads of current buffer complete past this point

    // ---- phase 3: stage (t+2, AH0) into current A (rows 0-127 now dead); quad (fr23, fc0)
    if (SM == 2) stage_half(aSrc, aC, koff + 128, 0);
    __builtin_amdgcn_s_setprio(1);
#pragma unroll
    for (int ks = 0; ks < 4; ++ks) {
        acc[2][0] = MFMA32(af[0][ks], bf0[ks], acc[2][0]);
        acc[3][0] = MFMA32(af[1][ks], bf0[ks], acc[3][0]);
    }
    __builtin_amdgcn_s_setprio(0);
    // drain all t+1 loads; only (t+2, AH0) may stay in flight
    if (SM == 2)      asm volatile("s_waitcnt vmcnt(2)" ::: "memory");
    else if (SM == 1) asm volatile("s_waitcnt vmcnt(0)" ::: "memory");
    BARRIER();
}

// ---------------- main GEMM: 256x256 tile, 8 waves, 32x32x16 pipeline ----------------
__global__ __launch_bounds__(512, 2) void w8a8_gemm256(
    const _Float16* __restrict__ Aq, const _Float16* __restrict__ Bq,
    const float* __restrict__ out_s, float* __restrict__ out)
{
    __shared__ _Float16 As[2 * 256 * 64];   // 64 KiB double-buffered A
    __shared__ _Float16 Bs[2 * 256 * 64];   // 64 KiB

    const int tid  = threadIdx.x;
    const int lane = tid & 63;
    const int wv   = tid >> 6;          // 0..7
    const int wm   = wv >> 2;           // 0..1
    const int wn   = wv & 3;            // 0..3
    const int l31  = lane & 31;
    const int lhi  = lane >> 5;         // 0..1
    const int x7   = lane & 7;

    // XCD-bijective tile map: 1376 = 8 XCDs x 172; XCD (id&7) owns tile-rows
    // 4x..4x+3 walked column-major (B-panel reuse in its L2; A+B set L3-resident).
    const int id = blockIdx.x;
    const int tn = id >> 5;                              // 0..42
    const int tm = ((id & 7) << 2) | ((id >> 3) & 3);    // 0..31

    const int row0 = tm * 256;
    const int col0 = tn * 256;

    // staging source: pre-swizzled global chunk (linear LDS dest + inverse-swz
    // source + swz read = involution)
    const int srow6  = tid >> 3;
    const int gchunk = (tid & 7) ^ (srow6 & 7);

    const _Float16* aSrc = Aq + (size_t)(row0 + srow6) * K_DIM + gchunk * 8;
    const _Float16* bSrc = Bq + (size_t)(col0 + srow6) * K_DIM + gchunk * 8;

    _Float16* aL0 = As + tid * 8;
    _Float16* aL1 = As + 16384 + tid * 8;
    _Float16* bL0 = Bs + tid * 8;
    _Float16* bL1 = Bs + 16384 + tid * 8;

    // per-lane read bases (halves) and swizzled k-slot offsets
    const int aRow = (wm * 128 + l31) * 64;
    const int bRow = (wn * 64  + l31) * 64;
    int so[4];
#pragma unroll
    for (int ks = 0; ks < 4; ++ks)
        so[ks] = ((2 * ks + lhi) ^ x7) * 8;

    f32x16 acc[4][2];
#pragma unroll
    for (int i = 0; i < 4; ++i)
#pragma unroll
        for (int j = 0; j < 2; ++j)
            acc[i][j] = (f32x16)0.0f;

    // prologue: tile 0 complete + (tile 1, AH0); keep only the newest 2 in flight
    stage_half(aSrc, aL0, 0, 0);      // (0, AH0)
    stage_half(aSrc, aL0, 0, 128);    // (0, AH1)
    stage_half(bSrc, bL0, 0, 0);      // (0, BH0)
    stage_half(bSrc, bL0, 0, 128);    // (0, BH1)
    stage_half(aSrc, aL1, 64, 0);     // (1, AH0)
    asm volatile("s_waitcnt vmcnt(2)" ::: "memory");
    BARRIER();

    for (int tt = 0; tt < 31; ++tt) {
        const int k0 = tt << 7;
        gemm_window<2>(aSrc, bSrc, k0,
                       As, Bs, aL1, bL1, aL0, aRow, bRow, so, acc);
        gemm_window<2>(aSrc, bSrc, k0 + 64,
                       As + 16384, Bs + 16384, aL0, bL0, aL1, aRow, bRow, so, acc);
    }
    gemm_window<1>(aSrc, bSrc, 62 * 64,
                   As, Bs, aL1, bL1, aL0, aRow, bRow, so, acc);
    gemm_window<0>(aSrc, bSrc, 63 * 64,
                   As + 16384, Bs + 16384, aL0, bL0, aL1, aRow, bRow, so, acc);

    // epilogue: 32x32 D mapping: col = lane&31, row = (reg&3) + 8*(reg>>2) + 4*(lane>>5)
    const int orow = row0 + wm * 128 + 4 * lhi;
    const int ocol = col0 + wn * 64 + l31;
#pragma unroll
    for (int fc = 0; fc < 2; ++fc) {
        const int n = ocol + fc * 32;
        const float sc = out_s[n];
#pragma unroll
        for (int fr = 0; fr < 4; ++fr) {
            const int rb = orow + fr * 32;
#pragma unroll
            for (int rg = 0; rg < 16; ++rg) {
                const int r = rb + (rg & 3) + 8 * (rg >> 2);
                __builtin_nontemporal_store(acc[fr][fc][rg] * sc,
                    out + (size_t)r * N_DIM + n);
            }
        }
    }
}

// ---------------- fallback (ws too small): prior verified 128x128 path ----------------
__global__ __launch_bounds__(256, 2) void w8a8_gemm_fb(
    const float* __restrict__ X, const int* __restrict__ Wt,
    const float* __restrict__ act_s, const float* __restrict__ out_s,
    float* __restrict__ out)
{
    __shared__ _Float16 As[128 * 64];
    __shared__ _Float16 Bs[128 * 64];

    const int tid  = threadIdx.x;
    const int lane = tid & 63;
    const int wv   = tid >> 6;
    const int wrow = (wv >> 1) * 64;
    const int wcol = (wv & 1) * 64;
    const int m16  = lane & 15;
    const int q4   = lane >> 4;
    const int xm   = m16 & 7;

    const int id   = blockIdx.x;
    const int gid  = (id & 7) * (FB_NB / 8) + (id >> 3);
    const int gsz  = FB_GROUP * FB_TN;
    const int grp  = gid / gsz;
    const int rem  = gid - grp * gsz;
    const int tn   = rem / FB_GROUP;
    const int tm   = grp * FB_GROUP + (rem - tn * FB_GROUP);

    const int row0 = tm * 128;
    const int col0 = tn * 128;

    const int srow = tid >> 3;
    const int sj   = (tid & 7) ^ (srow & 7);

    f32x4 acc[4][4];
#pragma unroll
    for (int i = 0; i < 4; ++i)
#pragma unroll
        for (int j = 0; j < 4; ++j)
            acc[i][j] = (f32x4)0.0f;

    const float inv = 1.0f / act_s[0];
    const float* xSrc = X  + (size_t)(row0 + srow) * K_DIM + sj * 8;
    const int*   wSrc = Wt + (size_t)(col0 + srow) * K_DIM + sj * 8;

    _Float16* aDst = As + tid * 8;
    _Float16* bDst = Bs + tid * 8;

    for (int kk = 0; kk < K_DIM / 64; ++kk) {
#pragma unroll
        for (int i = 0; i < 4; ++i) {
            const float4* p = (const float4*)(xSrc + (size_t)i * 32 * K_DIM);
            float4 v0 = p[0];
            float4 v1 = p[1];
            half8 h;
            h[0] = (_Float16)rintf(v0.x * inv);
            h[1] = (_Float16)rintf(v0.y * inv);
            h[2] = (_Float16)rintf(v0.z * inv);
            h[3] = (_Float16)rintf(v0.w * inv);
            h[4] = (_Float16)rintf(v1.x * inv);
            h[5] = (_Float16)rintf(v1.y * inv);
            h[6] = (_Float16)rintf(v1.z * inv);
            h[7] = (_Float16)rintf(v1.w * inv);
            *(half8*)(aDst + i * 256 * 8) = h;
        }
#pragma unroll
        for (int i = 0; i < 4; ++i) {
            const int4* p = (const int4*)(wSrc + (size_t)i * 32 * K_DIM);
            int4 v0 = p[0];
            int4 v1 = p[1];
            half8 h;
            h[0] = (_Float16)v0.x;
            h[1] = (_Float16)v0.y;
            h[2] = (_Float16)v0.z;
            h[3] = (_Float16)v0.w;
            h[4] = (_Float16)v1.x;
            h[5] = (_Float16)v1.y;
            h[6] = (_Float16)v1.z;
            h[7] = (_Float16)v1.w;
            *(half8*)(bDst + i * 256 * 8) = h;
        }
        xSrc += 64;
        wSrc += 64;

        __syncthreads();

#pragma unroll
        for (int s = 0; s < 2; ++s) {
            half8 af[4], bf[4];
            const int chunk = (s * 4 + q4) ^ xm;
#pragma unroll
            for (int t = 0; t < 4; ++t) {
                af[t] = *(const half8*)(As + (wrow + t * 16 + m16) * 64 + chunk * 8);
                bf[t] = *(const half8*)(Bs + (wcol + t * 16 + m16) * 64 + chunk * 8);
            }
#pragma unroll
            for (int ti = 0; ti < 4; ++ti)
#pragma unroll
                for (int tj = 0; tj < 4; ++tj)
                    acc[ti][tj] = MFMA16(af[ti], bf[tj], acc[ti][tj]);
        }
        __syncthreads();
    }

#pragma unroll
    for (int tj = 0; tj < 4; ++tj) {
        const int n = col0 + wcol + tj * 16 + m16;
        const float sc = out_s[n];
#pragma unroll
        for (int ti = 0; ti < 4; ++ti) {
            const int rbase = row0 + wrow + ti * 16 + q4 * 4;
#pragma unroll
            for (int r = 0; r < 4; ++r) {
                __builtin_nontemporal_store(acc[ti][tj][r] * sc,
                    out + (size_t)(rbase + r) * N_DIM + n);
            }
        }
    }
}

extern "C" void kernel_launch(void* const* d_in, const int* in_sizes, int n_in,
                              void* d_out, int out_size, void* d_ws, size_t ws_size,
                              hipStream_t stream) {
    const float* x     = (const float*)d_in[0];
    const int*   w     = (const int*)d_in[1];
    const float* act_s = (const float*)d_in[2];
    const float* out_s = (const float*)d_in[3];
    float* out = (float*)d_out;

    const size_t bytesA = (size_t)M_DIM * K_DIM * sizeof(_Float16);   // 64 MiB
    const size_t bytesB = (size_t)N_DIM * K_DIM * sizeof(_Float16);   // 86 MiB

    if (ws_size >= bytesA + bytesB) {
        _Float16* Aq = (_Float16*)d_ws;
        _Float16* Bq = (_Float16*)((char*)d_ws + bytesA);
        quant_x_kernel<<<(int)(((size_t)M_DIM * K_DIM) / 2048), 256, 0, stream>>>(x, act_s, Aq);
        quant_w_kernel<<<(int)(((size_t)N_DIM * K_DIM) / 2048), 256, 0, stream>>>(w, Bq);
        w8a8_gemm256<<<G_NB, 512, 0, stream>>>(Aq, Bq, out_s, out);
    } else {
        w8a8_gemm_fb<<<FB_NB, 256, 0, stream>>>(x, w, act_s, out_s, out);
    }
}

// Round 3
// 1118.547 us; speedup vs baseline: 1.0755x; 1.0755x over previous
//
#include <hip/hip_runtime.h>
#include <cstdint>
#include <cstddef>

// W8A8LinearStatic: out[m][n] = (sum_k round(x[m][k]/s_act) * W[n][k]) * out_scales[n]
// M=8192 (B*S), N=11008, K=4096. fp16 GEMM (exact: |q_x|<2048 integer, |W|<=127).
//
// R5: back to 16x16x32 MFMA (R1's measured 0-conflict LDS read pattern; R2's
// 32x32 was a structural 4-way bank conflict). Window restructured for
// read/MFMA overlap: only 2 barriers per K-window (pre-stage hazard + window
// end), fragments prefetched one phase ahead (peak 24 half8 = 96 VGPR,
// acc 128 AGPR = 256 unified budget @ 2 waves/SIMD), compiler-managed lgkmcnt,
// counted vmcnt(2) pipeline (loads never drained to 0 in steady state).

#define M_DIM 8192
#define N_DIM 11008
#define K_DIM 4096

#define G_TM 32                 // M/256
#define G_TN 43                 // N/256
#define G_NB (G_TM * G_TN)      // 1376 = 8 XCDs * 172
#define NT   (K_DIM / 64)       // 64 K-tiles of BK=64

#define FB_TM 64
#define FB_TN 86
#define FB_NB (FB_TM * FB_TN)
#define FB_GROUP 16

typedef _Float16 half8  __attribute__((ext_vector_type(8)));
typedef float    f32x4  __attribute__((ext_vector_type(4)));

#define GLOBAL_AS(p) ((const __attribute__((address_space(1))) void*)(p))
#define LDS_AS(p)    ((__attribute__((address_space(3))) void*)(p))

#define MFMA16(a,b,c) __builtin_amdgcn_mfma_f32_16x16x32_f16((a),(b),(c),0,0,0)

// raw s_barrier (no waitcnt drain) + compiler memory fence
#define BARRIER() do { asm volatile("" ::: "memory"); \
                       __builtin_amdgcn_s_barrier();  \
                       asm volatile("" ::: "memory"); } while (0)

// ---------------- quantize activations: q = rint(x * (1/s)), store fp16 ----------------
__global__ __launch_bounds__(256) void quant_x_kernel(
    const float* __restrict__ x, const float* __restrict__ act_s,
    _Float16* __restrict__ qx)
{
    const float inv = 1.0f / act_s[0];
    size_t idx = ((size_t)blockIdx.x * 256u + threadIdx.x) * 8u;
    const float4* p = (const float4*)(x + idx);
    float4 v0 = p[0];
    float4 v1 = p[1];
    half8 h;
    h[0] = (_Float16)rintf(v0.x * inv);
    h[1] = (_Float16)rintf(v0.y * inv);
    h[2] = (_Float16)rintf(v0.z * inv);
    h[3] = (_Float16)rintf(v0.w * inv);
    h[4] = (_Float16)rintf(v1.x * inv);
    h[5] = (_Float16)rintf(v1.y * inv);
    h[6] = (_Float16)rintf(v1.z * inv);
    h[7] = (_Float16)rintf(v1.w * inv);
    *(half8*)(qx + idx) = h;
}

// ---------------- convert weights: int32 (int8-valued) -> fp16 ----------------
__global__ __launch_bounds__(256) void quant_w_kernel(
    const int* __restrict__ w, _Float16* __restrict__ qw)
{
    size_t idx = ((size_t)blockIdx.x * 256u + threadIdx.x) * 8u;
    const int4* p = (const int4*)(w + idx);
    int4 v0 = p[0];
    int4 v1 = p[1];
    half8 h;
    h[0] = (_Float16)v0.x;
    h[1] = (_Float16)v0.y;
    h[2] = (_Float16)v0.z;
    h[3] = (_Float16)v0.w;
    h[4] = (_Float16)v1.x;
    h[5] = (_Float16)v1.y;
    h[6] = (_Float16)v1.z;
    h[7] = (_Float16)v1.w;
    *(half8*)(qw + idx) = h;
}

// ---------------- staging: one 128-row half-tile (2 x global_load_lds 16B) ----------
// LDS per buffer: 256 rows x 8 chunks of 16B, linear write; stored slot s of
// row r holds GLOBAL chunk s ^ (r&7) (source pre-swizzle; reads apply the same
// XOR -> involution).  src includes (row0 + tid>>3)*K + ((tid&7)^((tid>>3)&7))*8;
// lds includes buffer base + tid*8.
__device__ __forceinline__ void stage_half(const _Float16* __restrict__ src,
                                           _Float16* lds, int koff, int hrow)
{
    const _Float16* s = src + (size_t)hrow * K_DIM + koff;
    __builtin_amdgcn_global_load_lds(GLOBAL_AS(s),
        LDS_AS(lds + hrow * 64), 16, 0, 0);
    __builtin_amdgcn_global_load_lds(GLOBAL_AS(s + (size_t)64 * K_DIM),
        LDS_AS(lds + hrow * 64 + 4096), 16, 0, 0);
}

// ---------------- one K-tile window, 16x16x32, drift-friendly ----------------
// Wave tile 128x64 = 8x4 frags. Quadrants: (A-half, B-half), each 4x2 frags x
// 2 kchunks = 16 MFMA, order (0,0) (0,1) (1,1) (1,0).
// Reads: ph0: afh0(8)+bfh0(4)+bfh1(4); ph1: afh1(8). Compiler inserts counted
// lgkmcnt before each MFMA group; bfh1 drains under Q00, afh1 under Q01.
// Stages (SM==2): ph0: (t+1) BH0,BH1,AH1 -> next buffers; ph3: (t+2,AH0) ->
// current A buffer (rows 0-127 dead after the ph2-end barrier).
// Barriers: 2/window. vmcnt(2) at window end keeps only (t+2,AH0) in flight.
// SM: 2 steady / 1 (t==NT-2: stage t+1 only, vmcnt(0)) / 0 (t==NT-1).
template<int SM>
__device__ __forceinline__ void gemm_window(
    const _Float16* __restrict__ aSrc, const _Float16* __restrict__ bSrc,
    int koff,
    const _Float16* aT, const _Float16* bT,   // current LDS buffers
    _Float16* aN, _Float16* bN,               // next buffers (+ tid*8)
    _Float16* aC,                             // current A buffer (+ tid*8)
    int aBase, int bBase, int c0, int c1,
    f32x4 (&acc)[8][4])
{
    half8 af0[4][2], af1[4][2], bf0[2][2], bf1[2][2];

    // ---- ph0: reads for Q00 + B-half1 prefetch; issue all 6 next-tile stages
#pragma unroll
    for (int t = 0; t < 4; ++t) {
        af0[t][0] = *(const half8*)(aT + aBase + t * 1024 + c0);
        af0[t][1] = *(const half8*)(aT + aBase + t * 1024 + c1);
    }
#pragma unroll
    for (int t = 0; t < 2; ++t) {
        bf0[t][0] = *(const half8*)(bT + bBase + t * 1024 + c0);
        bf0[t][1] = *(const half8*)(bT + bBase + t * 1024 + c1);
    }
#pragma unroll
    for (int t = 0; t < 2; ++t) {
        bf1[t][0] = *(const half8*)(bT + bBase + 2048 + t * 1024 + c0);
        bf1[t][1] = *(const half8*)(bT + bBase + 2048 + t * 1024 + c1);
    }
    if (SM >= 1) {
        stage_half(bSrc, bN, koff + 64, 0);     // (t+1, BH0)
        stage_half(bSrc, bN, koff + 64, 128);   // (t+1, BH1)
        stage_half(aSrc, aN, koff + 64, 128);   // (t+1, AH1)
    }
    __builtin_amdgcn_s_setprio(1);
#pragma unroll
    for (int t = 0; t < 4; ++t)
#pragma unroll
        for (int u = 0; u < 2; ++u) {
            acc[t][u] = MFMA16(af0[t][0], bf0[u][0], acc[t][u]);
            acc[t][u] = MFMA16(af0[t][1], bf0[u][1], acc[t][u]);
        }
    __builtin_amdgcn_s_setprio(0);

    // ---- ph1: prefetch A-half1; Q01 (afh0 x bfh1)
#pragma unroll
    for (int t = 0; t < 4; ++t) {
        af1[t][0] = *(const half8*)(aT + aBase + 4096 + t * 1024 + c0);
        af1[t][1] = *(const half8*)(aT + aBase + 4096 + t * 1024 + c1);
    }
    __builtin_amdgcn_s_setprio(1);
#pragma unroll
    for (int t = 0; t < 4; ++t)
#pragma unroll
        for (int u = 0; u < 2; ++u) {
            acc[t][2 + u] = MFMA16(af0[t][0], bf1[u][0], acc[t][2 + u]);
            acc[t][2 + u] = MFMA16(af0[t][1], bf1[u][1], acc[t][2 + u]);
        }
    __builtin_amdgcn_s_setprio(0);

    // ---- ph2: Q11 (afh1 x bfh1)
    __builtin_amdgcn_s_setprio(1);
#pragma unroll
    for (int t = 0; t < 4; ++t)
#pragma unroll
        for (int u = 0; u < 2; ++u) {
            acc[4 + t][2 + u] = MFMA16(af1[t][0], bf1[u][0], acc[4 + t][2 + u]);
            acc[4 + t][2 + u] = MFMA16(af1[t][1], bf1[u][1], acc[4 + t][2 + u]);
        }
    __builtin_amdgcn_s_setprio(0);
    BARRIER();   // block-wide: all reads of current A buffer are retired

    // ---- ph3: stage (t+2, AH0) into current A; Q10 (afh1 x bfh0)
    if (SM == 2) stage_half(aSrc, aC, koff + 128, 0);
    __builtin_amdgcn_s_setprio(1);
#pragma unroll
    for (int t = 0; t < 4; ++t)
#pragma unroll
        for (int u = 0; u < 2; ++u) {
            acc[4 + t][u] = MFMA16(af1[t][0], bf0[u][0], acc[4 + t][u]);
            acc[4 + t][u] = MFMA16(af1[t][1], bf0[u][1], acc[4 + t][u]);
        }
    __builtin_amdgcn_s_setprio(0);
    // drain all (t+1) loads; only (t+2, AH0)'s 2 may stay in flight
    if (SM == 2)      asm volatile("s_waitcnt vmcnt(2)" ::: "memory");
    else if (SM == 1) asm volatile("s_waitcnt vmcnt(0)" ::: "memory");
    BARRIER();
}

// ---------------- main GEMM: 256x256 tile, 8 waves, 2-barrier window ----------------
__global__ __launch_bounds__(512, 2) void w8a8_gemm256(
    const _Float16* __restrict__ Aq, const _Float16* __restrict__ Bq,
    const float* __restrict__ out_s, float* __restrict__ out)
{
    __shared__ _Float16 As[2 * 256 * 64];   // 64 KiB double-buffered A
    __shared__ _Float16 Bs[2 * 256 * 64];   // 64 KiB

    const int tid  = threadIdx.x;
    const int lane = tid & 63;
    const int wv   = tid >> 6;          // 0..7
    const int wm   = wv >> 2;           // 0..1
    const int wn   = wv & 3;            // 0..3
    const int m16  = lane & 15;
    const int q4   = lane >> 4;         // 0..3
    const int xm   = m16 & 7;

    // XCD-bijective tile map: 1376 = 8 XCDs x 172; XCD (id&7) owns tile-rows
    // 4x..4x+3 walked column-major (B-panel reuse in its L2; A+B set L3-resident).
    const int id = blockIdx.x;
    const int tn = id >> 5;                              // 0..42
    const int tm = ((id & 7) << 2) | ((id >> 3) & 3);    // 0..31

    const int row0 = tm * 256;
    const int col0 = tn * 256;

    // staging source: pre-swizzled global chunk (linear LDS dest + inverse-swz
    // source + swz read = involution)
    const int srow6  = tid >> 3;
    const int gchunk = (tid & 7) ^ (srow6 & 7);

    const _Float16* aSrc = Aq + (size_t)(row0 + srow6) * K_DIM + gchunk * 8;
    const _Float16* bSrc = Bq + (size_t)(col0 + srow6) * K_DIM + gchunk * 8;

    _Float16* aL0 = As + tid * 8;
    _Float16* aL1 = As + 16384 + tid * 8;
    _Float16* bL0 = Bs + tid * 8;
    _Float16* bL1 = Bs + 16384 + tid * 8;

    // fragment read bases (halves): R1's measured 0-conflict pattern.
    // A frag t: row = wm*128 + (A-half)*64 + t*16 + m16; chunk = (s*4+q4)^xm.
    const int aBase = (wm * 128 + m16) * 64;
    const int bBase = (wn * 64  + m16) * 64;
    const int c0 = ((0 * 4 + q4) ^ xm) * 8;
    const int c1 = ((1 * 4 + q4) ^ xm) * 8;

    f32x4 acc[8][4];
#pragma unroll
    for (int i = 0; i < 8; ++i)
#pragma unroll
        for (int j = 0; j < 4; ++j)
            acc[i][j] = (f32x4)0.0f;

    // prologue: tile 0 complete + (tile 1, AH0); keep only the newest 2 in flight
    stage_half(aSrc, aL0, 0, 0);      // (0, AH0)
    stage_half(aSrc, aL0, 0, 128);    // (0, AH1)
    stage_half(bSrc, bL0, 0, 0);      // (0, BH0)
    stage_half(bSrc, bL0, 0, 128);    // (0, BH1)
    stage_half(aSrc, aL1, 64, 0);     // (1, AH0)
    asm volatile("s_waitcnt vmcnt(2)" ::: "memory");
    BARRIER();

    for (int tt = 0; tt < 31; ++tt) {
        const int k0 = tt << 7;
        gemm_window<2>(aSrc, bSrc, k0,
                       As, Bs, aL1, bL1, aL0, aBase, bBase, c0, c1, acc);
        gemm_window<2>(aSrc, bSrc, k0 + 64,
                       As + 16384, Bs + 16384, aL0, bL0, aL1, aBase, bBase, c0, c1, acc);
    }
    gemm_window<1>(aSrc, bSrc, 62 * 64,
                   As, Bs, aL1, bL1, aL0, aBase, bBase, c0, c1, acc);
    gemm_window<0>(aSrc, bSrc, 63 * 64,
                   As + 16384, Bs + 16384, aL0, bL0, aL1, aBase, bBase, c0, c1, acc);

    // epilogue: D mapping: col = lane&15, row = (lane>>4)*4 + reg.
    // Nontemporal: the 360MB output stream must not evict A/B panels.
#pragma unroll
    for (int bj = 0; bj < 4; ++bj) {
        const int n = col0 + wn * 64 + bj * 16 + m16;
        const float sc = out_s[n];
#pragma unroll
        for (int ai = 0; ai < 8; ++ai) {
            const int rbase = row0 + wm * 128 + ai * 16 + q4 * 4;
#pragma unroll
            for (int r = 0; r < 4; ++r) {
                __builtin_nontemporal_store(acc[ai][bj][r] * sc,
                    out + (size_t)(rbase + r) * N_DIM + n);
            }
        }
    }
}

// ---------------- fallback (ws too small): prior verified 128x128 path ----------------
__global__ __launch_bounds__(256, 2) void w8a8_gemm_fb(
    const float* __restrict__ X, const int* __restrict__ Wt,
    const float* __restrict__ act_s, const float* __restrict__ out_s,
    float* __restrict__ out)
{
    __shared__ _Float16 As[128 * 64];
    __shared__ _Float16 Bs[128 * 64];

    const int tid  = threadIdx.x;
    const int lane = tid & 63;
    const int wv   = tid >> 6;
    const int wrow = (wv >> 1) * 64;
    const int wcol = (wv & 1) * 64;
    const int m16  = lane & 15;
    const int q4   = lane >> 4;
    const int xm   = m16 & 7;

    const int id   = blockIdx.x;
    const int gid  = (id & 7) * (FB_NB / 8) + (id >> 3);
    const int gsz  = FB_GROUP * FB_TN;
    const int grp  = gid / gsz;
    const int rem  = gid - grp * gsz;
    const int tn   = rem / FB_GROUP;
    const int tm   = grp * FB_GROUP + (rem - tn * FB_GROUP);

    const int row0 = tm * 128;
    const int col0 = tn * 128;

    const int srow = tid >> 3;
    const int sj   = (tid & 7) ^ (srow & 7);

    f32x4 acc[4][4];
#pragma unroll
    for (int i = 0; i < 4; ++i)
#pragma unroll
        for (int j = 0; j < 4; ++j)
            acc[i][j] = (f32x4)0.0f;

    const float inv = 1.0f / act_s[0];
    const float* xSrc = X  + (size_t)(row0 + srow) * K_DIM + sj * 8;
    const int*   wSrc = Wt + (size_t)(col0 + srow) * K_DIM + sj * 8;

    _Float16* aDst = As + tid * 8;
    _Float16* bDst = Bs + tid * 8;

    for (int kk = 0; kk < K_DIM / 64; ++kk) {
#pragma unroll
        for (int i = 0; i < 4; ++i) {
            const float4* p = (const float4*)(xSrc + (size_t)i * 32 * K_DIM);
            float4 v0 = p[0];
            float4 v1 = p[1];
            half8 h;
            h[0] = (_Float16)rintf(v0.x * inv);
            h[1] = (_Float16)rintf(v0.y * inv);
            h[2] = (_Float16)rintf(v0.z * inv);
            h[3] = (_Float16)rintf(v0.w * inv);
            h[4] = (_Float16)rintf(v1.x * inv);
            h[5] = (_Float16)rintf(v1.y * inv);
            h[6] = (_Float16)rintf(v1.z * inv);
            h[7] = (_Float16)rintf(v1.w * inv);
            *(half8*)(aDst + i * 256 * 8) = h;
        }
#pragma unroll
        for (int i = 0; i < 4; ++i) {
            const int4* p = (const int4*)(wSrc + (size_t)i * 32 * K_DIM);
            int4 v0 = p[0];
            int4 v1 = p[1];
            half8 h;
            h[0] = (_Float16)v0.x;
            h[1] = (_Float16)v0.y;
            h[2] = (_Float16)v0.z;
            h[3] = (_Float16)v0.w;
            h[4] = (_Float16)v1.x;
            h[5] = (_Float16)v1.y;
            h[6] = (_Float16)v1.z;
            h[7] = (_Float16)v1.w;
            *(half8*)(bDst + i * 256 * 8) = h;
        }
        xSrc += 64;
        wSrc += 64;

        __syncthreads();

#pragma unroll
        for (int s = 0; s < 2; ++s) {
            half8 af[4], bf[4];
            const int chunk = (s * 4 + q4) ^ xm;
#pragma unroll
            for (int t = 0; t < 4; ++t) {
                af[t] = *(const half8*)(As + (wrow + t * 16 + m16) * 64 + chunk * 8);
                bf[t] = *(const half8*)(Bs + (wcol + t * 16 + m16) * 64 + chunk * 8);
            }
#pragma unroll
            for (int ti = 0; ti < 4; ++ti)
#pragma unroll
                for (int tj = 0; tj < 4; ++tj)
                    acc[ti][tj] = MFMA16(af[ti], bf[tj], acc[ti][tj]);
        }
        __syncthreads();
    }

#pragma unroll
    for (int tj = 0; tj < 4; ++tj) {
        const int n = col0 + wcol + tj * 16 + m16;
        const float sc = out_s[n];
#pragma unroll
        for (int ti = 0; ti < 4; ++ti) {
            const int rbase = row0 + wrow + ti * 16 + q4 * 4;
#pragma unroll
            for (int r = 0; r < 4; ++r) {
                __builtin_nontemporal_store(acc[ti][tj][r] * sc,
                    out + (size_t)(rbase + r) * N_DIM + n);
            }
        }
    }
}

extern "C" void kernel_launch(void* const* d_in, const int* in_sizes, int n_in,
                              void* d_out, int out_size, void* d_ws, size_t ws_size,
                              hipStream_t stream) {
    const float* x     = (const float*)d_in[0];
    const int*   w     = (const int*)d_in[1];
    const float* act_s = (const float*)d_in[2];
    const float* out_s = (const float*)d_in[3];
    float* out = (float*)d_out;

    const size_t bytesA = (size_t)M_DIM * K_DIM * sizeof(_Float16);   // 64 MiB
    const size_t bytesB = (size_t)N_DIM * K_DIM * sizeof(_Float16);   // 86 MiB

    if (ws_size >= bytesA + bytesB) {
        _Float16* Aq = (_Float16*)d_ws;
        _Float16* Bq = (_Float16*)((char*)d_ws + bytesA);
        quant_x_kernel<<<(int)(((size_t)M_DIM * K_DIM) / 2048), 256, 0, stream>>>(x, act_s, Aq);
        quant_w_kernel<<<(int)(((size_t)N_DIM * K_DIM) / 2048), 256, 0, stream>>>(w, Bq);
        w8a8_gemm256<<<G_NB, 512, 0, stream>>>(Aq, Bq, out_s, out);
    } else {
        w8a8_gemm_fb<<<FB_NB, 256, 0, stream>>>(x, w, act_s, out_s, out);
    }
}